// Round 6
// baseline (440.626 us; speedup 1.0000x reference)
//
#include <hip/hip_runtime.h>
#include <stdint.h>

#define NQ 10000
#define NC 2048
#define NW 157           // ceil(10000/64)
#define NR 79            // ceil(NW/2) rounds, 2 chunks per round
#define IOU_TH 0.5f

// -------- ws layout (bytes) --------
// scores : [0,       40000)
// rank   : [40000,   80000)
// boxes4 : [80000,  240000)   10000*4 f32 (xyxy, clipped+scaled)
// sx1    : [240000, 280000)   sorted SoA
// sy1    : [280000, 320000)
// sx2    : [320000, 360000)
// sy2    : [360000, 400000)
// sarea  : [400000, 440000)
// order  : [440000, 480000)   sorted index -> original index
// mask   : [480000, 480000+10000*157*8 = 13,040,000)

__global__ __launch_bounds__(256) void k_scores(const float* __restrict__ logits,
        float* __restrict__ out_scores, float* __restrict__ out_labels,
        float* __restrict__ ws_scores) {
    int wave = threadIdx.x >> 6;
    int lane = threadIdx.x & 63;
    int q = blockIdx.x * 4 + wave;
    if (q >= NQ) return;
    const float* row = logits + (size_t)q * NC;
    float4 v[8];
    float m = -3.4e38f;
    int am = 0;
    #pragma unroll
    for (int k = 0; k < 8; k++) {
        int idx = k * 256 + lane * 4;
        v[k] = *(const float4*)(row + idx);
        // strict > keeps first occurrence within this lane's ascending indices
        if (v[k].x > m) { m = v[k].x; am = idx; }
        if (v[k].y > m) { m = v[k].y; am = idx + 1; }
        if (v[k].z > m) { m = v[k].z; am = idx + 2; }
        if (v[k].w > m) { m = v[k].w; am = idx + 3; }
    }
    #pragma unroll
    for (int off = 32; off >= 1; off >>= 1) {
        float om = __shfl_xor(m, off);
        int   oa = __shfl_xor(am, off);
        if (om > m || (om == m && oa < am)) { m = om; am = oa; }
    }
    float s = 0.f;
    #pragma unroll
    for (int k = 0; k < 8; k++) {
        s += expf(v[k].x - m);
        s += expf(v[k].y - m);
        s += expf(v[k].z - m);
        s += expf(v[k].w - m);
    }
    #pragma unroll
    for (int off = 32; off >= 1; off >>= 1) s += __shfl_xor(s, off);
    if (lane == 0) {
        float sc = 1.0f / s;           // max prob = exp(0)/sum = 1/sum
        out_scores[q] = sc;
        out_labels[q] = (float)am;
        ws_scores[q]  = sc;
    }
}

__global__ __launch_bounds__(256) void k_cls(const float* __restrict__ cls,
                                             float* __restrict__ out) {
    float m = -3.4e38f; int am = 0x7fffffff;
    for (int idx = threadIdx.x; idx < NC; idx += 256) {
        float x = cls[idx];
        if (x > m) { m = x; am = idx; }    // per-thread indices ascending
    }
    int lane = threadIdx.x & 63, wave = threadIdx.x >> 6;
    #pragma unroll
    for (int off = 32; off >= 1; off >>= 1) {
        float om = __shfl_xor(m, off); int oa = __shfl_xor(am, off);
        if (om > m || (om == m && oa < am)) { m = om; am = oa; }
    }
    __shared__ float sm[4]; __shared__ int sa[4];
    if (lane == 0) { sm[wave] = m; sa[wave] = am; }
    __syncthreads();
    if (threadIdx.x == 0) {
        for (int w = 1; w < 4; w++)
            if (sm[w] > m || (sm[w] == m && sa[w] < am)) { m = sm[w]; am = sa[w]; }
        out[0] = (float)am;
    }
}

__global__ __launch_bounds__(256) void k_boxes(const float* __restrict__ pb,
        const int* __restrict__ ts, float* __restrict__ out_boxes,
        float* __restrict__ boxes4, int* __restrict__ rank) {
    #pragma clang fp contract(off)
    int i = blockIdx.x * 256 + threadIdx.x;
    if (i >= NQ) return;
    rank[i] = 0;
    // target_sizes may be int64 (low/high word pairs) or int32; values in [480,1333)
    int a0 = ts[0], a1 = ts[1];
    int ih, iw;
    if (a1 == 0) { ih = a0; iw = ts[2]; } else { ih = a0; iw = a1; }
    float sh = (float)ih, sw = (float)iw;
    float4 b = *(const float4*)(pb + i * 4);
    float x1 = b.x - 0.5f * b.z;
    float y1 = b.y - 0.5f * b.w;
    float x2 = b.x + 0.5f * b.z;
    float y2 = b.y + 0.5f * b.w;
    x1 = fminf(fmaxf(x1, 0.f), 1.f) * sw;
    y1 = fminf(fmaxf(y1, 0.f), 1.f) * sh;
    x2 = fminf(fmaxf(x2, 0.f), 1.f) * sw;
    y2 = fminf(fmaxf(y2, 0.f), 1.f) * sh;
    float4 o = make_float4(x1, y1, x2, y2);
    *(float4*)(out_boxes + i * 4) = o;
    *(float4*)(boxes4 + i * 4) = o;
}

// rank[i] = #{j: s_j > s_i} + #{j: s_j == s_i && j < i}  == position in argsort(-s) (stable)
__global__ __launch_bounds__(256) void k_count(const float* __restrict__ scores,
                                               int* __restrict__ rank) {
    __shared__ float sc[2000];
    int jbase = blockIdx.y * 2000;
    int jn = min(2000, NQ - jbase);
    for (int t = threadIdx.x; t < jn; t += 256) sc[t] = scores[jbase + t];
    __syncthreads();
    int i = blockIdx.x * 256 + threadIdx.x;
    if (i >= NQ) return;
    float si = scores[i];
    int cnt = 0;
    for (int jj = 0; jj < jn; jj++) {
        float sj = sc[jj];
        int j = jbase + jj;
        cnt += (sj > si) || (sj == si && j < i);
    }
    if (cnt) atomicAdd(&rank[i], cnt);
}

__global__ __launch_bounds__(256) void k_scatter(const float* __restrict__ boxes4,
        const int* __restrict__ rank, int* __restrict__ order,
        float* __restrict__ sx1, float* __restrict__ sy1,
        float* __restrict__ sx2, float* __restrict__ sy2,
        float* __restrict__ sarea) {
    #pragma clang fp contract(off)
    int i = blockIdx.x * 256 + threadIdx.x;
    if (i >= NQ) return;
    int r = rank[i];
    order[r] = i;
    float4 b = *(const float4*)(boxes4 + i * 4);
    sx1[r] = b.x; sy1[r] = b.y; sx2[r] = b.z; sy2[r] = b.w;
    sarea[r] = fmaxf(b.z - b.x, 0.f) * fmaxf(b.w - b.y, 0.f);
}

// mask[i][cb] bit jj = (j>i) && IoU(i, j)>0.5, j = cb*64+jj (sorted order)
__global__ __launch_bounds__(64) void k_mask(const float* __restrict__ sx1,
        const float* __restrict__ sy1, const float* __restrict__ sx2,
        const float* __restrict__ sy2, const float* __restrict__ sarea,
        unsigned long long* __restrict__ mask) {
    #pragma clang fp contract(off)
    int rb = blockIdx.x, cb = blockIdx.y;
    if (cb < rb) return;
    int t = threadIdx.x;
    __shared__ float cx1[64], cy1[64], cx2[64], cy2[64], ca[64];
    int j0 = cb * 64 + t;
    if (j0 < NQ) { cx1[t]=sx1[j0]; cy1[t]=sy1[j0]; cx2[t]=sx2[j0]; cy2[t]=sy2[j0]; ca[t]=sarea[j0]; }
    __syncthreads();
    int i = rb * 64 + t;
    if (i >= NQ) return;
    float xi1 = sx1[i], yi1 = sy1[i], xi2 = sx2[i], yi2 = sy2[i], ai = sarea[i];
    int ncol = min(64, NQ - cb * 64);
    unsigned long long word = 0;
    for (int jj = 0; jj < ncol; jj++) {
        int j = cb * 64 + jj;
        float lx = fmaxf(xi1, cx1[jj]);
        float ly = fmaxf(yi1, cy1[jj]);
        float rx = fminf(xi2, cx2[jj]);
        float ry = fminf(yi2, cy2[jj]);
        float w = fmaxf(rx - lx, 0.f);
        float h = fmaxf(ry - ly, 0.f);
        float inter = w * h;
        float denom = (ai + ca[jj]) - inter;   // ref op order: (areas[i]+areas)-inter
        float iou = inter / denom;
        bool sup = (iou > IOU_TH) && (j > i);
        word |= ((unsigned long long)(sup ? 1u : 0u)) << jj;
    }
    mask[(size_t)i * NW + cb] = word;
}

__device__ __forceinline__ unsigned long long bcast64(unsigned long long v) {
    uint32_t lo = (uint32_t)__builtin_amdgcn_readfirstlane((int)(uint32_t)v);
    uint32_t hi = (uint32_t)__builtin_amdgcn_readfirstlane((int)(uint32_t)(v >> 32));
    return ((unsigned long long)hi << 32) | lo;
}

// Greedy reduce, v7: 2 chunks (128 rows) per round -> per-round fixed costs
// (barriers, LDS latency, broadcasts, bulk issue) amortized over 2x rows.
// Round r handles a=2r, b=2r+1. Staged columns (wave 1, one round ahead,
// parity buffers): stA[k][l] = mask[a*64+l][a+k] k=0..3 (diag, cross a->b,
// crit c2, crit c3); stB[k][l] = mask[b*64+l][b+k] k=0..2 (diag, c2, c3).
// Duties:
//   wave 0, A: resolve(a) with cross-fold (xAB readlanes accumulate kept(a)'s
//     suppression of chunk b, off the ctz chain) then resolve(b); publish.
//   wave 0, B: crit words c2=2r+2, c3=2r+3: per-lane kept-masked OR of staged
//     columns, 6-step __shfl_xor reduce, single-lane |= into rem[] (replaces
//     the serialized same-address LDS atomicOr of v6).
//   waves 1-3, A: consume pending bulk (vmcnt stall overlaps wave0's resolve);
//     wave 1 then issues next round's 7 stage loads (contiguous words/row).
//   waves 1-3, B: bulk issue for words w>=2r+4: thread t owns w=2r+4+(t-64)
//     (192 threads >= 153 max words); 32 named slots over kept0 then kept1
//     rows, padded with the first kept row (OR-idempotent); overflow
//     (kept0+kept1>32, early rounds only) via exposed 8-batches. Wave 1 also
//     writes its staged columns to LDS (stage loads drained here, ~a full
//     phase after issue).
// Races: A: wave0 reads rem[2r],rem[2r+1]; bulk(r-1) consume atomicOrs
// rem[w>=2r+2] - disjoint. B: wave0 lane0 is the only rem writer (c2,c3);
// bulk(r-1) contributions to c2/c3 landed at A(r) - barrier-separated.
// Coverage: word 2r: m2(r-1) + bulk(r'<=r-2) [bulk(r-2) covers w>=2r];
// word 2r+1: AcB(r) + m3(r-1) + bulk(r'<=r-2). Complete.
__global__ __launch_bounds__(256, 1) void k_scan(const unsigned long long* __restrict__ mask,
        const int* __restrict__ order, float* __restrict__ out_keep) {
    __shared__ unsigned long long rem[NW];
    __shared__ unsigned long long keepw[NW];
    __shared__ unsigned long long stA[2][4][64];
    __shared__ unsigned long long stB[2][3][64];
    __shared__ unsigned long long sh_k0, sh_k1;

    const int tid  = threadIdx.x;
    const int wave = tid >> 6;
    const int lane = tid & 63;

    for (int w = tid; w < NW; w += 256) rem[w] = 0;

    // ---- prologue: wave 1 stages round 0 (parity 0) ----
    if (wave == 1) {
        uint64_t sA0=0,sA1=0,sA2=0,sA3=0,sB0=0,sB1=0,sB2=0;
        int ra = lane, rb = 64 + lane;
        {
            const unsigned long long* rp = mask + (size_t)ra * NW;
            sA0 = rp[0]; sA1 = rp[1]; sA2 = rp[2]; sA3 = rp[3];
        }
        {
            const unsigned long long* rp = mask + (size_t)rb * NW;
            sB0 = rp[1]; sB1 = rp[2]; sB2 = rp[3];
        }
        stA[0][0][lane]=sA0; stA[0][1][lane]=sA1; stA[0][2][lane]=sA2; stA[0][3][lane]=sA3;
        stB[0][0][lane]=sB0; stB[0][1][lane]=sB1; stB[0][2][lane]=sB2;
    }
    __syncthreads();

    // pending bulk state (waves 1-3)
    uint64_t pp0=0,pp1=0,pp2=0,pp3=0,pp4=0,pp5=0,pp6=0,pp7=0;
    uint64_t pp8=0,pp9=0,pp10=0,pp11=0,pp12=0,pp13=0,pp14=0,pp15=0;
    uint64_t pp16=0,pp17=0,pp18=0,pp19=0,pp20=0,pp21=0,pp22=0,pp23=0;
    uint64_t pp24=0,pp25=0,pp26=0,pp27=0,pp28=0,pp29=0,pp30=0,pp31=0;
    uint64_t pex = 0;
    int pw = -1;

    uint64_t kept0 = 0, kept1 = 0;    // wave 0's SGPR copies

    for (int r = 0; r < NR; r++) {
        const int a = 2 * r, b = a + 1;
        const int par = r & 1;

        // stage regs (wave 1, this iteration A->B)
        uint64_t sA0=0,sA1=0,sA2=0,sA3=0,sB0=0,sB1=0,sB2=0;

        // ======================= phase A =======================
        if (wave == 0) {
            // LDS reads up front
            uint64_t remA_v = rem[a];
            uint64_t remB_v = (b < NW) ? rem[b] : ~0ull;
            uint64_t dgA = stA[par][0][lane];
            uint64_t xAB = stA[par][1][lane];
            uint64_t dgB = (b < NW) ? stB[par][0][lane] : 0;

            // ---- resolve chunk a (cross-fold into AcB) ----
            uint64_t cur0 = bcast64(remA_v);
            int nv0 = min(64, NQ - a * 64);
            if (nv0 < 64) cur0 |= (~0ull) << nv0;
            uint32_t dglo = (uint32_t)dgA, dghi = (uint32_t)(dgA >> 32);
            uint32_t xlo  = (uint32_t)xAB, xhi  = (uint32_t)(xAB >> 32);
            uint64_t alive = ~cur0;
            uint64_t k0 = 0, AcB = 0;
            while (alive) {
                int bb = (int)__builtin_ctzll(alive);
                uint64_t d = ((uint64_t)(uint32_t)__builtin_amdgcn_readlane((int)dghi, bb) << 32)
                           | (uint32_t)__builtin_amdgcn_readlane((int)dglo, bb);
                uint64_t x = ((uint64_t)(uint32_t)__builtin_amdgcn_readlane((int)xhi, bb) << 32)
                           | (uint32_t)__builtin_amdgcn_readlane((int)xlo, bb);
                k0    |= 1ull << bb;
                cur0  |= d;
                AcB   |= x;                  // off the ctz chain
                alive &= ~(d | (1ull << bb));
            }
            kept0 = k0;

            // ---- resolve chunk b ----
            uint64_t k1 = 0, cur1 = 0;
            if (b < NW) {
                cur1 = bcast64(remB_v) | AcB;
                int nv1 = min(64, NQ - b * 64);
                if (nv1 < 64) cur1 |= (~0ull) << nv1;
                uint32_t blo = (uint32_t)dgB, bhi = (uint32_t)(dgB >> 32);
                uint64_t alv = ~cur1;
                while (alv) {
                    int bb = (int)__builtin_ctzll(alv);
                    uint64_t d = ((uint64_t)(uint32_t)__builtin_amdgcn_readlane((int)bhi, bb) << 32)
                               | (uint32_t)__builtin_amdgcn_readlane((int)blo, bb);
                    k1  |= 1ull << bb;
                    cur1 |= d;
                    alv &= ~(d | (1ull << bb));
                }
            }
            kept1 = k1;
            if (tid == 0) {
                sh_k0 = k0; sh_k1 = k1;
                keepw[a] = cur0;
                if (b < NW) keepw[b] = cur1;
            }
        } else {
            // consume pending bulk(r-1); vmcnt stall overlaps wave0's resolve
            if (pw >= 0) {
                uint64_t pacc = (((pp0|pp1)|(pp2|pp3)) | ((pp4|pp5)|(pp6|pp7)))
                              | (((pp8|pp9)|(pp10|pp11)) | ((pp12|pp13)|(pp14|pp15)));
                pacc |= (((pp16|pp17)|(pp18|pp19)) | ((pp20|pp21)|(pp22|pp23)))
                      | (((pp24|pp25)|(pp26|pp27)) | ((pp28|pp29)|(pp30|pp31)));
                pacc |= pex;
                if (pacc) atomicOr(&rem[pw], (unsigned long long)pacc);
            }
            pw = -1;

            if (wave == 1) {
                // issue next round's stage loads (consume's wait already done)
                int a2 = a + 2, b2 = a + 3;
                int ra = a2 * 64 + lane, rb = b2 * 64 + lane;
                if (a2 < NW && ra < NQ) {
                    const unsigned long long* rp = mask + (size_t)ra * NW + a2;
                    sA0 = rp[0];
                    if (a2 + 1 < NW) sA1 = rp[1];
                    if (a2 + 2 < NW) sA2 = rp[2];
                    if (a2 + 3 < NW) sA3 = rp[3];
                }
                if (b2 < NW && rb < NQ) {
                    const unsigned long long* rp = mask + (size_t)rb * NW + b2;
                    sB0 = rp[0];
                    if (b2 + 1 < NW) sB1 = rp[1];
                    if (b2 + 2 < NW) sB2 = rp[2];
                }
            }
        }
        __syncthreads();   // barrier 1: kept/keepw published

        // ======================= phase B =======================
        const int c2 = a + 2, c3 = a + 3;
        if (wave == 0) {
            // critical words via shuffle-reduce (kept0/kept1 already in SGPRs)
            if (c2 < NW) {
                uint64_t vA2 = stA[par][2][lane];
                uint64_t vB1 = (b < NW) ? stB[par][1][lane] : 0;
                uint64_t m2 = (((kept0 >> lane) & 1ull) ? vA2 : 0)
                            | (((kept1 >> lane) & 1ull) ? vB1 : 0);
                uint64_t m3 = 0;
                if (c3 < NW) {
                    uint64_t vA3 = stA[par][3][lane];
                    uint64_t vB2 = (b < NW) ? stB[par][2][lane] : 0;
                    m3 = (((kept0 >> lane) & 1ull) ? vA3 : 0)
                       | (((kept1 >> lane) & 1ull) ? vB2 : 0);
                }
                #pragma unroll
                for (int off = 32; off >= 1; off >>= 1) {
                    m2 |= __shfl_xor(m2, off);
                    m3 |= __shfl_xor(m3, off);
                }
                if (lane == 0) {
                    rem[c2] |= m2;                 // sole rem writer in phase B
                    if (c3 < NW) rem[c3] |= m3;
                }
            }
        } else {
            // broadcast kept masks
            uint64_t k0 = bcast64(sh_k0);
            uint64_t k1 = bcast64(sh_k1);

            if (wave == 1) {
                // stage write first: drains stage loads (issued ~1 phase ago)
                // BEFORE the bulk issue, keeping the consume-wait at A(r+1)
                // covering only bulk loads.
                int par2 = (r + 1) & 1;
                stA[par2][0][lane]=sA0; stA[par2][1][lane]=sA1;
                stA[par2][2][lane]=sA2; stA[par2][3][lane]=sA3;
                stB[par2][0][lane]=sB0; stB[par2][1][lane]=sB1; stB[par2][2][lane]=sB2;
            }

            int w = a + 4 + (tid - 64);
            if ((k0 | k1) && w < NW) {
                const unsigned long long* baseA = mask + (size_t)(a * 64) * NW + w;
                const unsigned long long* baseB = mask + (size_t)(b * 64) * NW + w;
                uint64_t km0 = k0, km1 = k1;
                const unsigned long long* fb =
                    km0 ? baseA + (size_t)__builtin_ctzll(km0) * NW
                        : baseB + (size_t)__builtin_ctzll(km1) * NW;
                #define BULK_SLOT(P) { const unsigned long long* rp; \
                    if (km0)      { rp = baseA + (size_t)__builtin_ctzll(km0) * NW; km0 &= km0 - 1; } \
                    else if (km1) { rp = baseB + (size_t)__builtin_ctzll(km1) * NW; km1 &= km1 - 1; } \
                    else rp = fb; \
                    P = rp[0]; }
                BULK_SLOT(pp0)  BULK_SLOT(pp1)  BULK_SLOT(pp2)  BULK_SLOT(pp3)
                BULK_SLOT(pp4)  BULK_SLOT(pp5)  BULK_SLOT(pp6)  BULK_SLOT(pp7)
                BULK_SLOT(pp8)  BULK_SLOT(pp9)  BULK_SLOT(pp10) BULK_SLOT(pp11)
                BULK_SLOT(pp12) BULK_SLOT(pp13) BULK_SLOT(pp14) BULK_SLOT(pp15)
                BULK_SLOT(pp16) BULK_SLOT(pp17) BULK_SLOT(pp18) BULK_SLOT(pp19)
                BULK_SLOT(pp20) BULK_SLOT(pp21) BULK_SLOT(pp22) BULK_SLOT(pp23)
                BULK_SLOT(pp24) BULK_SLOT(pp25) BULK_SLOT(pp26) BULK_SLOT(pp27)
                BULK_SLOT(pp28) BULK_SLOT(pp29) BULK_SLOT(pp30) BULK_SLOT(pp31)
                // overflow (kept0+kept1 > 32): exposed 8-batches (early rounds)
                pex = 0;
                while (km0 | km1) {
                    uint64_t x0,x1,x2,x3,x4,x5,x6,x7;
                    BULK_SLOT(x0) BULK_SLOT(x1) BULK_SLOT(x2) BULK_SLOT(x3)
                    BULK_SLOT(x4) BULK_SLOT(x5) BULK_SLOT(x6) BULK_SLOT(x7)
                    pex |= (x0|x1)|(x2|x3)|((x4|x5)|(x6|x7));
                }
                #undef BULK_SLOT
                pw = w;
            } else {
                pw = -1; pex = 0;
            }
        }
        __syncthreads();   // barrier 2: rem[c2],rem[c3] final; stage written
    }

    // ================= epilogue: parallel keep writeback =================
    for (int si = tid; si < NQ; si += 256) {
        unsigned long long kw = keepw[si >> 6];
        out_keep[order[si]] = ((kw >> (si & 63)) & 1ull) ? 0.f : 1.f;
    }
}

extern "C" void kernel_launch(void* const* d_in, const int* in_sizes, int n_in,
                              void* d_out, int out_size, void* d_ws, size_t ws_size,
                              hipStream_t stream) {
    const float* pred_logits = (const float*)d_in[0];
    const float* pred_boxes  = (const float*)d_in[1];
    const float* cls_logits  = (const float*)d_in[2];
    const int*   tsizes      = (const int*)d_in[3];

    float* out = (float*)d_out;
    float* out_scores = out;
    float* out_labels = out + 10000;
    float* out_boxes  = out + 20000;
    float* out_keep   = out + 60000;
    float* out_cls    = out + 70000;

    char* ws = (char*)d_ws;
    float* ws_scores = (float*)(ws + 0);
    int*   rank      = (int*)  (ws + 40000);
    float* boxes4    = (float*)(ws + 80000);
    float* sx1       = (float*)(ws + 240000);
    float* sy1       = (float*)(ws + 280000);
    float* sx2       = (float*)(ws + 320000);
    float* sy2       = (float*)(ws + 360000);
    float* sarea     = (float*)(ws + 400000);
    int*   order     = (int*)  (ws + 440000);
    unsigned long long* mask = (unsigned long long*)(ws + 480000);

    k_scores<<<2500, 256, 0, stream>>>(pred_logits, out_scores, out_labels, ws_scores);
    k_cls<<<1, 256, 0, stream>>>(cls_logits, out_cls);
    k_boxes<<<40, 256, 0, stream>>>(pred_boxes, tsizes, out_boxes, boxes4, rank);
    k_count<<<dim3(40, 5), 256, 0, stream>>>(ws_scores, rank);
    k_scatter<<<40, 256, 0, stream>>>(boxes4, rank, order, sx1, sy1, sx2, sy2, sarea);
    k_mask<<<dim3(157, 157), 64, 0, stream>>>(sx1, sy1, sx2, sy2, sarea, mask);
    k_scan<<<1, 256, 0, stream>>>(mask, order, out_keep);
}

// Round 7
// 423.812 us; speedup vs baseline: 1.0397x; 1.0397x over previous
//
#include <hip/hip_runtime.h>
#include <stdint.h>
#include <math.h>

#define NQ 10000
#define NC 2048
#define NW 157           // ceil(10000/64)
#define NR 79            // ceil(NW/2) rounds, 2 chunks per round
#define NTRI 12403       // NW*(NW+1)/2 upper-triangle blocks
#define IOU_TH 0.5f

// -------- ws layout (bytes) --------
// scores : [0,       40000)
// rank   : [40000,   80000)
// boxes4 : [80000,  240000)   10000*4 f32 (xyxy, clipped+scaled)
// sx1    : [240000, 280000)   sorted SoA
// sy1    : [280000, 320000)
// sx2    : [320000, 360000)
// sy2    : [360000, 400000)
// sarea  : [400000, 440000)
// order  : [440000, 480000)   sorted index -> original index
// mask   : [480000, 480000+10000*157*8 = 13,040,000)

// Fused front-end: blocks 0..2499 = per-query softmax scores; block 2500 =
// cls argmax; blocks 2501..2540 = box convert/clip/scale. One launch
// instead of three (launch overhead is material at ~0.6-0.7GHz idle clock).
__global__ __launch_bounds__(256) void k_front(const float* __restrict__ logits,
        const float* __restrict__ cls, const float* __restrict__ pb,
        const int* __restrict__ ts,
        float* __restrict__ out_scores, float* __restrict__ out_labels,
        float* __restrict__ out_cls, float* __restrict__ out_boxes,
        float* __restrict__ ws_scores, float* __restrict__ boxes4,
        int* __restrict__ rank) {
    int bx = blockIdx.x;
    if (bx < 2500) {
        int wave = threadIdx.x >> 6;
        int lane = threadIdx.x & 63;
        int q = bx * 4 + wave;
        if (q >= NQ) return;
        const float* row = logits + (size_t)q * NC;
        float4 v[8];
        float m = -3.4e38f;
        int am = 0;
        #pragma unroll
        for (int k = 0; k < 8; k++) {
            int idx = k * 256 + lane * 4;
            v[k] = *(const float4*)(row + idx);
            // strict > keeps first occurrence within this lane's ascending indices
            if (v[k].x > m) { m = v[k].x; am = idx; }
            if (v[k].y > m) { m = v[k].y; am = idx + 1; }
            if (v[k].z > m) { m = v[k].z; am = idx + 2; }
            if (v[k].w > m) { m = v[k].w; am = idx + 3; }
        }
        #pragma unroll
        for (int off = 32; off >= 1; off >>= 1) {
            float om = __shfl_xor(m, off);
            int   oa = __shfl_xor(am, off);
            if (om > m || (om == m && oa < am)) { m = om; am = oa; }
        }
        float s = 0.f;
        #pragma unroll
        for (int k = 0; k < 8; k++) {
            s += expf(v[k].x - m);
            s += expf(v[k].y - m);
            s += expf(v[k].z - m);
            s += expf(v[k].w - m);
        }
        #pragma unroll
        for (int off = 32; off >= 1; off >>= 1) s += __shfl_xor(s, off);
        if (lane == 0) {
            float sc = 1.0f / s;           // max prob = exp(0)/sum = 1/sum
            out_scores[q] = sc;
            out_labels[q] = (float)am;
            ws_scores[q]  = sc;
        }
        return;
    }
    if (bx == 2500) {
        float m = -3.4e38f; int am = 0x7fffffff;
        for (int idx = threadIdx.x; idx < NC; idx += 256) {
            float x = cls[idx];
            if (x > m) { m = x; am = idx; }    // per-thread indices ascending
        }
        int lane = threadIdx.x & 63, wave = threadIdx.x >> 6;
        #pragma unroll
        for (int off = 32; off >= 1; off >>= 1) {
            float om = __shfl_xor(m, off); int oa = __shfl_xor(am, off);
            if (om > m || (om == m && oa < am)) { m = om; am = oa; }
        }
        __shared__ float sm[4]; __shared__ int sa[4];
        if (lane == 0) { sm[wave] = m; sa[wave] = am; }
        __syncthreads();
        if (threadIdx.x == 0) {
            for (int w = 1; w < 4; w++)
                if (sm[w] > m || (sm[w] == m && sa[w] < am)) { m = sm[w]; am = sa[w]; }
            out_cls[0] = (float)am;
        }
        return;
    }
    {
        #pragma clang fp contract(off)
        int i = (bx - 2501) * 256 + threadIdx.x;
        if (i >= NQ) return;
        rank[i] = 0;
        // target_sizes may be int64 (low/high word pairs) or int32; values in [480,1333)
        int a0 = ts[0], a1 = ts[1];
        int ih, iw;
        if (a1 == 0) { ih = a0; iw = ts[2]; } else { ih = a0; iw = a1; }
        float sh = (float)ih, sw = (float)iw;
        float4 b = *(const float4*)(pb + i * 4);
        float x1 = b.x - 0.5f * b.z;
        float y1 = b.y - 0.5f * b.w;
        float x2 = b.x + 0.5f * b.z;
        float y2 = b.y + 0.5f * b.w;
        x1 = fminf(fmaxf(x1, 0.f), 1.f) * sw;
        y1 = fminf(fmaxf(y1, 0.f), 1.f) * sh;
        x2 = fminf(fmaxf(x2, 0.f), 1.f) * sw;
        y2 = fminf(fmaxf(y2, 0.f), 1.f) * sh;
        float4 o = make_float4(x1, y1, x2, y2);
        *(float4*)(out_boxes + i * 4) = o;
        *(float4*)(boxes4 + i * 4) = o;
    }
}

// rank[i] = #{j: s_j > s_i} + #{j: s_j == s_i && j < i}  == position in argsort(-s)
// jn is always 2000 (NQ = 5*2000), so the tile is read as 500 float4s.
__global__ __launch_bounds__(256) void k_count(const float* __restrict__ scores,
                                               int* __restrict__ rank) {
    __shared__ float4 sc4[500];
    int jbase = blockIdx.y * 2000;
    const float4* src = (const float4*)(scores + jbase);
    for (int t = threadIdx.x; t < 500; t += 256) sc4[t] = src[t];
    __syncthreads();
    int i = blockIdx.x * 256 + threadIdx.x;
    if (i >= NQ) return;
    float si = scores[i];
    int cnt = 0;
    #pragma unroll 2
    for (int q = 0; q < 500; q++) {
        float4 v = sc4[q];
        int j = jbase + 4 * q;
        cnt += (v.x > si) || (v.x == si && j     < i);
        cnt += (v.y > si) || (v.y == si && j + 1 < i);
        cnt += (v.z > si) || (v.z == si && j + 2 < i);
        cnt += (v.w > si) || (v.w == si && j + 3 < i);
    }
    if (cnt) atomicAdd(&rank[i], cnt);
}

__global__ __launch_bounds__(256) void k_scatter(const float* __restrict__ boxes4,
        const int* __restrict__ rank, int* __restrict__ order,
        float* __restrict__ sx1, float* __restrict__ sy1,
        float* __restrict__ sx2, float* __restrict__ sy2,
        float* __restrict__ sarea) {
    #pragma clang fp contract(off)
    int i = blockIdx.x * 256 + threadIdx.x;
    if (i >= NQ) return;
    int r = rank[i];
    order[r] = i;
    float4 b = *(const float4*)(boxes4 + i * 4);
    sx1[r] = b.x; sy1[r] = b.y; sx2[r] = b.z; sy2[r] = b.w;
    sarea[r] = fmaxf(b.z - b.x, 0.f) * fmaxf(b.w - b.y, 0.f);
}

// mask[i][cb] bit jj = (j>i) && IoU(i,j)>0.5 (sorted order). 1D upper-triangle
// grid: block t -> (rb,cb) with cb>=rb; removes the 12,246 dead cb<rb blocks.
__global__ __launch_bounds__(64) void k_mask(const float* __restrict__ sx1,
        const float* __restrict__ sy1, const float* __restrict__ sx2,
        const float* __restrict__ sy2, const float* __restrict__ sarea,
        unsigned long long* __restrict__ mask) {
    #pragma clang fp contract(off)
    int tri = blockIdx.x;
    // S(r) = r*NW - r*(r-1)/2 entries precede row r; invert via sqrt + fixup
    int rb = (int)((2.0 * NW + 1.0
              - sqrt((double)((2 * NW + 1) * (2 * NW + 1) - 8 * tri))) * 0.5);
    while (rb > 0 && rb * NW - rb * (rb - 1) / 2 > tri) rb--;
    while ((rb + 1) * NW - (rb + 1) * rb / 2 <= tri) rb++;
    int cb = rb + (tri - (rb * NW - rb * (rb - 1) / 2));

    int t = threadIdx.x;
    __shared__ float cx1[64], cy1[64], cx2[64], cy2[64], ca[64];
    int j0 = cb * 64 + t;
    if (j0 < NQ) { cx1[t]=sx1[j0]; cy1[t]=sy1[j0]; cx2[t]=sx2[j0]; cy2[t]=sy2[j0]; ca[t]=sarea[j0]; }
    __syncthreads();
    int i = rb * 64 + t;
    if (i >= NQ) return;
    float xi1 = sx1[i], yi1 = sy1[i], xi2 = sx2[i], yi2 = sy2[i], ai = sarea[i];
    int ncol = min(64, NQ - cb * 64);
    unsigned long long word = 0;
    for (int jj = 0; jj < ncol; jj++) {
        int j = cb * 64 + jj;
        float lx = fmaxf(xi1, cx1[jj]);
        float ly = fmaxf(yi1, cy1[jj]);
        float rx = fminf(xi2, cx2[jj]);
        float ry = fminf(yi2, cy2[jj]);
        float w = fmaxf(rx - lx, 0.f);
        float h = fmaxf(ry - ly, 0.f);
        float inter = w * h;
        float denom = (ai + ca[jj]) - inter;   // ref op order: (areas[i]+areas)-inter
        float iou = inter / denom;
        bool sup = (iou > IOU_TH) && (j > i);
        word |= ((unsigned long long)(sup ? 1u : 0u)) << jj;
    }
    mask[(size_t)i * NW + cb] = word;
}

__device__ __forceinline__ unsigned long long bcast64(unsigned long long v) {
    uint32_t lo = (uint32_t)__builtin_amdgcn_readfirstlane((int)(uint32_t)v);
    uint32_t hi = (uint32_t)__builtin_amdgcn_readfirstlane((int)(uint32_t)(v >> 32));
    return ((unsigned long long)hi << 32) | lo;
}

// Greedy reduce, v8 = v7 structure + two fixes:
//   (1) stage loads issued ONE FULL ROUND early: B(r) writes stage(r+1) from
//       regs issued in B(r-1) (already drained by A(r)'s bulk consume ->
//       zero-stall ds_write), then issues loads for round r+2.
//   (2) resolve chain shortened: readlane dfull = diag | self-bit (precomputed
//       per lane) -> per-step chain is ff1 -> readlane -> andn2. cur collects
//       self-bits during the loop and is fixed once at the end (cur &= ~kept).
// Everything else identical to v7 (see its race/coverage audit).
__global__ __launch_bounds__(256, 1) void k_scan(const unsigned long long* __restrict__ mask,
        const int* __restrict__ order, float* __restrict__ out_keep) {
    __shared__ unsigned long long rem[NW];
    __shared__ unsigned long long keepw[NW];
    __shared__ unsigned long long stA[2][4][64];
    __shared__ unsigned long long stB[2][3][64];
    __shared__ unsigned long long sh_k0, sh_k1;

    const int tid  = threadIdx.x;
    const int wave = tid >> 6;
    const int lane = tid & 63;

    for (int w = tid; w < NW; w += 256) rem[w] = 0;

    // stage regs for wave 1 (persist round-to-round; loads for round r+2
    // issued in B(r), written to LDS in B(r+1))
    uint64_t sA0=0,sA1=0,sA2=0,sA3=0,sB0=0,sB1=0,sB2=0;

    // ---- prologue: wave 1 direct-stages round 0, then issues round 1 ----
    if (wave == 1) {
        {
            const unsigned long long* rp = mask + (size_t)lane * NW;
            stA[0][0][lane]=rp[0]; stA[0][1][lane]=rp[1];
            stA[0][2][lane]=rp[2]; stA[0][3][lane]=rp[3];
            const unsigned long long* rq = mask + (size_t)(64 + lane) * NW;
            stB[0][0][lane]=rq[1]; stB[0][1][lane]=rq[2]; stB[0][2][lane]=rq[3];
        }
        {   // round 1: a2=2 (rows 128+lane), b2=3 (rows 192+lane); words in range
            const unsigned long long* rp = mask + (size_t)(128 + lane) * NW + 2;
            sA0=rp[0]; sA1=rp[1]; sA2=rp[2]; sA3=rp[3];
            const unsigned long long* rq = mask + (size_t)(192 + lane) * NW + 3;
            sB0=rq[0]; sB1=rq[1]; sB2=rq[2];
        }
    }
    __syncthreads();

    // pending bulk state (waves 1-3)
    uint64_t pp0=0,pp1=0,pp2=0,pp3=0,pp4=0,pp5=0,pp6=0,pp7=0;
    uint64_t pp8=0,pp9=0,pp10=0,pp11=0,pp12=0,pp13=0,pp14=0,pp15=0;
    uint64_t pp16=0,pp17=0,pp18=0,pp19=0,pp20=0,pp21=0,pp22=0,pp23=0;
    uint64_t pp24=0,pp25=0,pp26=0,pp27=0,pp28=0,pp29=0,pp30=0,pp31=0;
    uint64_t pex = 0;
    int pw = -1;

    uint64_t kept0 = 0, kept1 = 0;    // wave 0's SGPR copies

    for (int r = 0; r < NR; r++) {
        const int a = 2 * r, b = a + 1;
        const int par = r & 1;

        // ======================= phase A =======================
        if (wave == 0) {
            // LDS reads up front (independent -> overlapped)
            uint64_t remA_v = rem[a];
            uint64_t remB_v = (b < NW) ? rem[b] : ~0ull;
            uint64_t dgA = stA[par][0][lane];
            uint64_t xAB = stA[par][1][lane];
            uint64_t dgB = (b < NW) ? stB[par][0][lane] : 0;
            uint64_t dfA = dgA | (1ull << lane);    // dfull: diag + self bit
            uint64_t dfB = dgB | (1ull << lane);

            // ---- resolve chunk a (cross-fold into AcB) ----
            uint64_t cur0 = bcast64(remA_v);
            int nv0 = min(64, NQ - a * 64);
            if (nv0 < 64) cur0 |= (~0ull) << nv0;
            uint32_t dflo = (uint32_t)dfA, dfhi = (uint32_t)(dfA >> 32);
            uint32_t xlo  = (uint32_t)xAB, xhi  = (uint32_t)(xAB >> 32);
            uint64_t alive = ~cur0;
            uint64_t k0 = 0, AcB = 0;
            while (alive) {
                int bb = (int)__builtin_ctzll(alive);
                uint64_t df = ((uint64_t)(uint32_t)__builtin_amdgcn_readlane((int)dfhi, bb) << 32)
                            | (uint32_t)__builtin_amdgcn_readlane((int)dflo, bb);
                uint64_t x  = ((uint64_t)(uint32_t)__builtin_amdgcn_readlane((int)xhi, bb) << 32)
                            | (uint32_t)__builtin_amdgcn_readlane((int)xlo, bb);
                k0    |= 1ull << bb;          // off-chain
                cur0  |= df;                  // off-chain (self bits fixed below)
                AcB   |= x;                   // off-chain
                alive &= ~df;                 // the chain: ff1 -> readlane -> andn2
            }
            cur0 &= ~k0;                      // clear kept rows' self bits
            kept0 = k0;

            // ---- resolve chunk b ----
            uint64_t k1 = 0, cur1 = 0;
            if (b < NW) {
                cur1 = bcast64(remB_v) | AcB;
                int nv1 = min(64, NQ - b * 64);
                if (nv1 < 64) cur1 |= (~0ull) << nv1;
                uint32_t blo = (uint32_t)dfB, bhi = (uint32_t)(dfB >> 32);
                uint64_t alv = ~cur1;
                while (alv) {
                    int bb = (int)__builtin_ctzll(alv);
                    uint64_t df = ((uint64_t)(uint32_t)__builtin_amdgcn_readlane((int)bhi, bb) << 32)
                                | (uint32_t)__builtin_amdgcn_readlane((int)blo, bb);
                    k1  |= 1ull << bb;
                    cur1 |= df;
                    alv &= ~df;
                }
                cur1 &= ~k1;
            }
            kept1 = k1;
            if (tid == 0) {
                sh_k0 = k0; sh_k1 = k1;
                keepw[a] = cur0;
                if (b < NW) keepw[b] = cur1;
            }
        } else {
            // consume pending bulk(r-1); vmcnt stall overlaps wave0's resolve
            if (pw >= 0) {
                uint64_t pacc = (((pp0|pp1)|(pp2|pp3)) | ((pp4|pp5)|(pp6|pp7)))
                              | (((pp8|pp9)|(pp10|pp11)) | ((pp12|pp13)|(pp14|pp15)));
                pacc |= (((pp16|pp17)|(pp18|pp19)) | ((pp20|pp21)|(pp22|pp23)))
                      | (((pp24|pp25)|(pp26|pp27)) | ((pp28|pp29)|(pp30|pp31)));
                pacc |= pex;
                if (pacc) atomicOr(&rem[pw], (unsigned long long)pacc);
            }
            pw = -1;
        }
        __syncthreads();   // barrier 1: kept/keepw published

        // ======================= phase B =======================
        const int c2 = a + 2, c3 = a + 3;
        if (wave == 0) {
            // critical words via shuffle-reduce (kept0/kept1 already in SGPRs)
            if (c2 < NW) {
                uint64_t vA2 = stA[par][2][lane];
                uint64_t vB1 = (b < NW) ? stB[par][1][lane] : 0;
                uint64_t m2 = (((kept0 >> lane) & 1ull) ? vA2 : 0)
                            | (((kept1 >> lane) & 1ull) ? vB1 : 0);
                uint64_t m3 = 0;
                if (c3 < NW) {
                    uint64_t vA3 = stA[par][3][lane];
                    uint64_t vB2 = (b < NW) ? stB[par][2][lane] : 0;
                    m3 = (((kept0 >> lane) & 1ull) ? vA3 : 0)
                       | (((kept1 >> lane) & 1ull) ? vB2 : 0);
                }
                #pragma unroll
                for (int off = 32; off >= 1; off >>= 1) {
                    m2 |= __shfl_xor(m2, off);
                    m3 |= __shfl_xor(m3, off);
                }
                if (lane == 0) {
                    rem[c2] |= m2;                 // sole rem writer in phase B
                    if (c3 < NW) rem[c3] |= m3;
                }
            }
        } else {
            // broadcast kept masks
            uint64_t k0 = bcast64(sh_k0);
            uint64_t k1 = bcast64(sh_k1);

            if (wave == 1) {
                // (1) write stage(r+1): loads issued in B(r-1), already drained
                //     by this round's A-consume -> no stall.
                int par2 = (r + 1) & 1;
                stA[par2][0][lane]=sA0; stA[par2][1][lane]=sA1;
                stA[par2][2][lane]=sA2; stA[par2][3][lane]=sA3;
                stB[par2][0][lane]=sB0; stB[par2][1][lane]=sB1; stB[par2][2][lane]=sB2;
                // (2) issue loads for round r+2
                sA0=sA1=sA2=sA3=sB0=sB1=sB2=0;
                int rr = r + 2;
                if (rr < NR) {
                    int a2 = 2 * rr, b2 = a2 + 1;
                    int ra = a2 * 64 + lane, rbw = b2 * 64 + lane;
                    if (a2 < NW && ra < NQ) {
                        const unsigned long long* rp = mask + (size_t)ra * NW + a2;
                        sA0 = rp[0];
                        if (a2 + 1 < NW) sA1 = rp[1];
                        if (a2 + 2 < NW) sA2 = rp[2];
                        if (a2 + 3 < NW) sA3 = rp[3];
                    }
                    if (b2 < NW && rbw < NQ) {
                        const unsigned long long* rq = mask + (size_t)rbw * NW + b2;
                        sB0 = rq[0];
                        if (b2 + 1 < NW) sB1 = rq[1];
                        if (b2 + 2 < NW) sB2 = rq[2];
                    }
                }
            }

            int w = a + 4 + (tid - 64);
            if ((k0 | k1) && w < NW) {
                const unsigned long long* baseA = mask + (size_t)(a * 64) * NW + w;
                const unsigned long long* baseB = mask + (size_t)(b * 64) * NW + w;
                uint64_t km0 = k0, km1 = k1;
                const unsigned long long* fb =
                    km0 ? baseA + (size_t)__builtin_ctzll(km0) * NW
                        : baseB + (size_t)__builtin_ctzll(km1) * NW;
                #define BULK_SLOT(P) { const unsigned long long* rp; \
                    if (km0)      { rp = baseA + (size_t)__builtin_ctzll(km0) * NW; km0 &= km0 - 1; } \
                    else if (km1) { rp = baseB + (size_t)__builtin_ctzll(km1) * NW; km1 &= km1 - 1; } \
                    else rp = fb; \
                    P = rp[0]; }
                BULK_SLOT(pp0)  BULK_SLOT(pp1)  BULK_SLOT(pp2)  BULK_SLOT(pp3)
                BULK_SLOT(pp4)  BULK_SLOT(pp5)  BULK_SLOT(pp6)  BULK_SLOT(pp7)
                BULK_SLOT(pp8)  BULK_SLOT(pp9)  BULK_SLOT(pp10) BULK_SLOT(pp11)
                BULK_SLOT(pp12) BULK_SLOT(pp13) BULK_SLOT(pp14) BULK_SLOT(pp15)
                BULK_SLOT(pp16) BULK_SLOT(pp17) BULK_SLOT(pp18) BULK_SLOT(pp19)
                BULK_SLOT(pp20) BULK_SLOT(pp21) BULK_SLOT(pp22) BULK_SLOT(pp23)
                BULK_SLOT(pp24) BULK_SLOT(pp25) BULK_SLOT(pp26) BULK_SLOT(pp27)
                BULK_SLOT(pp28) BULK_SLOT(pp29) BULK_SLOT(pp30) BULK_SLOT(pp31)
                // overflow (kept0+kept1 > 32): exposed 8-batches (early rounds)
                pex = 0;
                while (km0 | km1) {
                    uint64_t x0,x1,x2,x3,x4,x5,x6,x7;
                    BULK_SLOT(x0) BULK_SLOT(x1) BULK_SLOT(x2) BULK_SLOT(x3)
                    BULK_SLOT(x4) BULK_SLOT(x5) BULK_SLOT(x6) BULK_SLOT(x7)
                    pex |= (x0|x1)|(x2|x3)|((x4|x5)|(x6|x7));
                }
                #undef BULK_SLOT
                pw = w;
            } else {
                pw = -1; pex = 0;
            }
        }
        __syncthreads();   // barrier 2: rem[c2],rem[c3] final; stage written
    }

    // ================= epilogue: parallel keep writeback =================
    for (int si = tid; si < NQ; si += 256) {
        unsigned long long kw = keepw[si >> 6];
        out_keep[order[si]] = ((kw >> (si & 63)) & 1ull) ? 0.f : 1.f;
    }
}

extern "C" void kernel_launch(void* const* d_in, const int* in_sizes, int n_in,
                              void* d_out, int out_size, void* d_ws, size_t ws_size,
                              hipStream_t stream) {
    const float* pred_logits = (const float*)d_in[0];
    const float* pred_boxes  = (const float*)d_in[1];
    const float* cls_logits  = (const float*)d_in[2];
    const int*   tsizes      = (const int*)d_in[3];

    float* out = (float*)d_out;
    float* out_scores = out;
    float* out_labels = out + 10000;
    float* out_boxes  = out + 20000;
    float* out_keep   = out + 60000;
    float* out_cls    = out + 70000;

    char* ws = (char*)d_ws;
    float* ws_scores = (float*)(ws + 0);
    int*   rank      = (int*)  (ws + 40000);
    float* boxes4    = (float*)(ws + 80000);
    float* sx1       = (float*)(ws + 240000);
    float* sy1       = (float*)(ws + 280000);
    float* sx2       = (float*)(ws + 320000);
    float* sy2       = (float*)(ws + 360000);
    float* sarea     = (float*)(ws + 400000);
    int*   order     = (int*)  (ws + 440000);
    unsigned long long* mask = (unsigned long long*)(ws + 480000);

    k_front<<<2541, 256, 0, stream>>>(pred_logits, cls_logits, pred_boxes, tsizes,
                                      out_scores, out_labels, out_cls, out_boxes,
                                      ws_scores, boxes4, rank);
    k_count<<<dim3(40, 5), 256, 0, stream>>>(ws_scores, rank);
    k_scatter<<<40, 256, 0, stream>>>(boxes4, rank, order, sx1, sy1, sx2, sy2, sarea);
    k_mask<<<NTRI, 64, 0, stream>>>(sx1, sy1, sx2, sy2, sarea, mask);
    k_scan<<<1, 256, 0, stream>>>(mask, order, out_keep);
}